// Round 9
// baseline (230.652 us; speedup 1.0000x reference)
//
#include <hip/hip_runtime.h>

#define NN 100000
#define NE 1600000
#define ET (NE + NN)      // logical edges incl. self-loops
#define NG 256
#define NEG_SLOPE 0.2f
#define SM_EPS 1e-16f

// ---- two-level bucketed CSR build ----
#define BSHIFT 7                       // bucket = dst >> 7 (128 nodes/bucket)
#define NBUCK ((NN + 127) / 128)       // 782
#define EPB 8192                       // edges per block in count/fill passes
#define NBLK ((ET + EPB - 1) / EPB)    // 208
#define MAXB 5120                      // LDS staging cap (max bucket ~2400)

typedef _Float16 half8 __attribute__((ext_vector_type(8)));

__device__ __forceinline__ float lrelu(float x) { return x > 0.0f ? x : NEG_SLOPE * x; }

__device__ __forceinline__ void edge_sd(const int* __restrict__ src,
                                        const int* __restrict__ dst,
                                        int e, int& s, int& d) {
    if (e < NE) { s = src[e]; d = dst[e]; } else { s = e - NE; d = s; }
}

// ---- A1: per-block per-bucket counts (dst only) ----
__global__ void k_countA(const int* __restrict__ dst, int* __restrict__ bcnt) {
    __shared__ int cnt[NBUCK];
    int t = threadIdx.x, bid = blockIdx.x;
    for (int i = t; i < NBUCK; i += 256) cnt[i] = 0;
    __syncthreads();
    int e0 = bid * EPB;
    #pragma unroll
    for (int k = 0; k < EPB / 256; ++k) {
        int e = e0 + k * 256 + t;
        if (e < ET) {
            int d = (e < NE) ? dst[e] : (e - NE);
            atomicAdd(&cnt[d >> BSHIFT], 1);
        }
    }
    __syncthreads();
    for (int i = t; i < NBUCK; i += 256) bcnt[i * NBLK + bid] = cnt[i];
}

// ---- A2a: per-bucket exclusive prefix over blocks ----
__global__ void k_scanrow(int* __restrict__ bcnt, int* __restrict__ gcnt) {
    int row = blockIdx.x, lane = threadIdx.x;   // 64 threads
    int running = 0;
    const int chunks = (NBLK + 63) / 64;
    for (int c = 0; c < chunks; ++c) {
        int i = c * 64 + lane;
        int v = (i < NBLK) ? bcnt[row * NBLK + i] : 0;
        int incl = v;
        #pragma unroll
        for (int o = 1; o < 64; o <<= 1) {
            int u = __shfl_up(incl, o, 64);
            if (lane >= o) incl += u;
        }
        if (i < NBLK) bcnt[row * NBLK + i] = running + (incl - v);
        running += __shfl(incl, 63, 64);
    }
    if (lane == 0) gcnt[row] = running;
}

// ---- A2b: exclusive scan of bucket totals ----
__global__ void k_gscan(const int* __restrict__ gcnt, int* __restrict__ gbase) {
    __shared__ int sm[1024];
    int t = threadIdx.x;
    int v = (t < NBUCK) ? gcnt[t] : 0;
    sm[t] = v;
    __syncthreads();
    for (int off = 1; off < 1024; off <<= 1) {
        int u = (t >= off) ? sm[t - off] : 0;
        __syncthreads();
        sm[t] += u;
        __syncthreads();
    }
    if (t < NBUCK) gbase[t] = sm[t] - v;
}

// ---- A3: fill compact bucket-major packed edge array ((s<<7)|(d&127)) ----
__global__ void k_fillA(const int* __restrict__ src, const int* __restrict__ dst,
                        const int* __restrict__ bcnt, const int* __restrict__ gbase,
                        int* __restrict__ bedge) {
    __shared__ int base[NBUCK];
    __shared__ int lcnt[NBUCK];
    int t = threadIdx.x, bid = blockIdx.x;
    for (int i = t; i < NBUCK; i += 256) {
        base[i] = gbase[i] + bcnt[i * NBLK + bid];
        lcnt[i] = 0;
    }
    __syncthreads();
    int e0 = bid * EPB;
    #pragma unroll
    for (int k = 0; k < EPB / 256; ++k) {
        int e = e0 + k * 256 + t;
        if (e < ET) {
            int s, d; edge_sd(src, dst, e, s, d);
            int b = d >> BSHIFT;
            int rank = atomicAdd(&lcnt[b], 1);
            bedge[base[b] + rank] = (s << 7) | (d & 127);
        }
    }
}

// ---- B: per-bucket LDS counting sort -> coalesced CSR + deg + row_start ----
__global__ void k_sortB(const int* __restrict__ gcnt, const int* __restrict__ gbase,
                        const int* __restrict__ bedge,
                        int* __restrict__ csr_src, int* __restrict__ deg,
                        int* __restrict__ row_start) {
    __shared__ int lcnt[128], lstart[128], lcur[128];
    __shared__ int lout[MAXB];
    int b = blockIdx.x, t = threadIdx.x;        // 256 threads
    int cnt = gcnt[b];
    int base = gbase[b];
    const int* eb = bedge + base;
    if (t < 128) lcnt[t] = 0;
    __syncthreads();
    for (int i = t; i < cnt; i += 256)
        atomicAdd(&lcnt[eb[i] & 127], 1);
    __syncthreads();
    if (t < 128) lstart[t] = lcnt[t];
    __syncthreads();
    for (int off = 1; off < 128; off <<= 1) {
        int v = (t >= off && t < 128) ? lstart[t - off] : 0;
        __syncthreads();
        if (t < 128) lstart[t] += v;
        __syncthreads();
    }
    if (t < 128) {
        lstart[t] -= lcnt[t];          // exclusive
        lcur[t] = lstart[t];
    }
    __syncthreads();
    for (int i = t; i < cnt; i += 256) {
        int p = eb[i];
        int pos = atomicAdd(&lcur[p & 127], 1);
        lout[pos] = p >> 7;
    }
    __syncthreads();
    for (int i = t; i < cnt; i += 256)
        csr_src[base + i] = lout[i];
    int n = (b << BSHIFT) + t;
    if (t < 128 && n < NN) {
        deg[n] = lcnt[t];
        row_start[n] = base + lstart[t];
    }
}

// ---- layer-1 folded coefficients: c1s = W1·a1s, c1d = W1·a1d ----
__global__ void k_c1(const float* __restrict__ W1, const float* __restrict__ a1s,
                     const float* __restrict__ a1d, float2* __restrict__ c12) {
    int t = threadIdx.x;  // 64
    float w  = (t < 32) ? W1[t] : 0.0f;
    float vs = (t < 32) ? w * a1s[t] : 0.0f;
    float vd = (t < 32) ? w * a1d[t] : 0.0f;
    #pragma unroll
    for (int o = 32; o; o >>= 1) {
        vs += __shfl_xor(vs, o, 64);
        vd += __shfl_xor(vd, o, 64);
    }
    if (t == 0) *c12 = make_float2(vs, vd);
}

// ---- layer-2 folded score coefficients: c2s = W2@a2s, c2d = W2@a2d (32-vec) ----
__global__ void k_c2(const float* __restrict__ W2, const float* __restrict__ a2s,
                     const float* __restrict__ a2d,
                     float* __restrict__ c2s, float* __restrict__ c2d) {
    int k = threadIdx.x;   // 64 threads, first 32 active
    if (k >= 32) return;
    float vs = 0.0f, vd = 0.0f;
    for (int f = 0; f < 64; ++f) {
        float w = W2[k * 64 + f];
        vs += w * a2s[f];
        vd += w * a2d[f];
    }
    c2s[k] = vs; c2d[k] = vd;
}

// ---- layer 1: scalar GAT (rank-1 structure), one wave per node ----
__global__ void k_gat1(const int* __restrict__ row_start, const int* __restrict__ deg,
                       const int* __restrict__ csr_src, const float* __restrict__ x,
                       const float2* __restrict__ c12, float* __restrict__ Y) {
    int wid = (blockIdx.x * blockDim.x + threadIdx.x) >> 6;
    int lane = threadIdx.x & 63;
    if (wid >= NN) return;
    float2 c = *c12;                 // wave-uniform
    float xd = x[wid];
    int start = row_start[wid];
    int dg = deg[wid];

    float xs_reg = 0.0f, alpha_reg = -1e30f, m = -1e30f;
    if (lane < dg) {
        int s = csr_src[start + lane];
        xs_reg = x[s];
        alpha_reg = lrelu(c.x * xs_reg + c.y * xd);
        m = alpha_reg;
    }
    for (int i = lane + 64; i < dg; i += 64) {      // rare tail
        float xs = x[csr_src[start + i]];
        m = fmaxf(m, lrelu(c.x * xs + c.y * xd));
    }
    #pragma unroll
    for (int o = 32; o; o >>= 1) m = fmaxf(m, __shfl_xor(m, o, 64));

    float ev = (lane < dg) ? __expf(alpha_reg - m) : 0.0f;
    float sum = ev, wy = ev * xs_reg;
    for (int i = lane + 64; i < dg; i += 64) {      // rare tail
        float xs = x[csr_src[start + i]];
        float e2 = __expf(lrelu(c.x * xs + c.y * xd) - m);
        sum += e2; wy += e2 * xs;
    }
    #pragma unroll
    for (int o = 32; o; o >>= 1) {
        sum += __shfl_xor(sum, o, 64);
        wy  += __shfl_xor(wy, o, 64);
    }
    if (lane == 0) Y[wid] = wy / (sum + SM_EPS);
}

// ---- layer 2 pre: x2 = relu(Y*W1+b1) (fp16, NN x 32); ss/ds via folded c2 ----
__global__ void k5_x2(const float* __restrict__ Y,
                      const float* __restrict__ W1, const float* __restrict__ b1,
                      const float* __restrict__ c2s, const float* __restrict__ c2d,
                      _Float16* __restrict__ x2h,
                      float* __restrict__ ss, float* __restrict__ ds) {
    int tid = blockIdx.x * blockDim.x + threadIdx.x;
    if (tid >= NN * 32) return;
    int n = tid >> 5, k = tid & 31;
    float xv = Y[n] * W1[k] + b1[k];
    xv = xv > 0.0f ? xv : 0.0f;
    x2h[tid] = (_Float16)xv;
    float vs = xv * c2s[k];
    float vd = xv * c2d[k];
    #pragma unroll
    for (int m = 16; m; m >>= 1) {
        vs += __shfl_xor(vs, m, 32);
        vd += __shfl_xor(vd, m, 32);
    }
    if (k == 0) { ss[n] = vs; ds[n] = vd; }
}

// ---- layer 2 GAT: fp16 x2 gather (32-dim), 16 edges concurrent, Z = agg(x2) ----
__global__ void k_gat2(const int* __restrict__ row_start, const int* __restrict__ deg,
                       const int* __restrict__ csr_src,
                       const float* __restrict__ ss, const float* __restrict__ ds,
                       const half8* __restrict__ x2h, float* __restrict__ Z) {
    int wid = (blockIdx.x * blockDim.x + threadIdx.x) >> 6;
    int lane = threadIdx.x & 63;
    if (wid >= NN) return;
    int start = row_start[wid];
    int dg = deg[wid];
    float dsv = ds[wid];

    int   s_reg = 0;
    float alpha_reg = -1e30f, m = -1e30f;
    if (lane < dg) {
        s_reg = csr_src[start + lane];
        alpha_reg = lrelu(ss[s_reg] + dsv);
        m = alpha_reg;
    }
    for (int i = lane + 64; i < dg; i += 64) {
        int s = csr_src[start + i];
        m = fmaxf(m, lrelu(ss[s] + dsv));
    }
    #pragma unroll
    for (int o = 32; o; o >>= 1) m = fmaxf(m, __shfl_xor(m, o, 64));

    float sum = (lane < dg) ? __expf(alpha_reg - m) : 0.0f;
    for (int i = lane + 64; i < dg; i += 64) {
        int s = csr_src[start + i];
        sum += __expf(lrelu(ss[s] + dsv) - m);
    }
    #pragma unroll
    for (int o = 32; o; o >>= 1) sum += __shfl_xor(sum, o, 64);
    float inv = 1.0f / (sum + SM_EPS);

    // 16 edge-groups x half8 (8 features)/lane; uniform rounds for shfl safety
    int g  = lane >> 2;                 // edge group 0..15
    int f8 = lane & 3;                  // half8 index within 32 features
    float acc[8] = {0, 0, 0, 0, 0, 0, 0, 0};
    int nfull = dg < 64 ? dg : 64;
    int rounds = (nfull + 15) / 16;                 // wave-uniform
    for (int k = 0; k < rounds; ++k) {
        int t = g + k * 16;                         // <= 63 always
        int   s = __shfl(s_reg, t, 64);
        float a = __shfl(alpha_reg, t, 64);
        if (t < nfull) {
            float ev = __expf(a - m);
            half8 hv = x2h[(size_t)s * 4 + f8];
            #pragma unroll
            for (int j = 0; j < 8; ++j) acc[j] += ev * (float)hv[j];
        }
    }
    for (int t = 64 + g; t < dg; t += 16) {         // rare tail
        int s = csr_src[start + t];
        float ev = __expf(lrelu(ss[s] + dsv) - m);
        half8 hv = x2h[(size_t)s * 4 + f8];
        #pragma unroll
        for (int j = 0; j < 8; ++j) acc[j] += ev * (float)hv[j];
    }
    #pragma unroll
    for (int o = 4; o < 64; o <<= 1)
        #pragma unroll
        for (int j = 0; j < 8; ++j) acc[j] += __shfl_xor(acc[j], o, 64);
    if (lane < 4) {
        float4* dst = (float4*)&Z[(size_t)wid * 32 + lane * 8];
        dst[0] = make_float4(acc[0] * inv, acc[1] * inv, acc[2] * inv, acc[3] * inv);
        dst[1] = make_float4(acc[4] * inv, acc[5] * inv, acc[6] * inv, acc[7] * inv);
    }
}

// ---- fused post-projection + relu + segmented pool ----
// wave per 64-node chunk; lane = output feature f; W2 column in registers.
#define POOL_CHUNK 64
__global__ void k_post_pool(const float* __restrict__ Z,
                            const float* __restrict__ W2, const float* __restrict__ b2,
                            const int* __restrict__ batch,
                            float* __restrict__ pooled, float* __restrict__ cnts) {
    int wid = (blockIdx.x * blockDim.x + threadIdx.x) >> 6;
    int lane = threadIdx.x & 63;
    int n0 = wid * POOL_CHUNK;
    if (n0 >= NN) return;
    int n1 = n0 + POOL_CHUNK; if (n1 > NN) n1 = NN;
    float w2r[32];
    #pragma unroll
    for (int k = 0; k < 32; ++k) w2r[k] = W2[k * 64 + lane];   // coalesced
    float bv = b2[lane];
    int curg = batch[n0];
    float acc = 0.0f;
    int cnt = 0;
    for (int n = n0; n < n1; ++n) {
        int g = batch[n];                       // wave-uniform
        if (g != curg) {
            atomicAdd(&pooled[curg * 64 + lane], acc);
            if (lane == 0) atomicAdd(&cnts[curg], (float)cnt);
            acc = 0.0f; cnt = 0; curg = g;
        }
        const float* zr = &Z[(size_t)n * 32];   // wave-uniform row
        float v = bv;
        #pragma unroll
        for (int k = 0; k < 32; ++k) v += zr[k] * w2r[k];
        acc += v > 0.0f ? v : 0.0f;
        ++cnt;
    }
    atomicAdd(&pooled[curg * 64 + lane], acc);
    if (lane == 0) atomicAdd(&cnts[curg], (float)cnt);
}

__global__ void k7_fc(const float* __restrict__ pooled, const float* __restrict__ cnts,
                      const float* __restrict__ fcW, const float* __restrict__ fcb,
                      float* __restrict__ out) {
    int g = threadIdx.x;
    if (g >= NG) return;
    float c = fmaxf(cnts[g], 1.0f);
    float o0 = fcb[0], o1 = fcb[1];
    for (int f = 0; f < 64; ++f) {
        float p = pooled[g * 64 + f] / c;
        o0 += p * fcW[f * 2 + 0];
        o1 += p * fcW[f * 2 + 1];
    }
    out[g * 2 + 0] = o0;
    out[g * 2 + 1] = o1;
}

extern "C" void kernel_launch(void* const* d_in, const int* in_sizes, int n_in,
                              void* d_out, int out_size, void* d_ws, size_t ws_size,
                              hipStream_t stream) {
    const float* x    = (const float*)d_in[0];
    const int*   ei   = (const int*)d_in[1];
    const int*   src  = ei;
    const int*   dst  = ei + NE;
    const int*   batch= (const int*)d_in[2];
    const float* W1   = (const float*)d_in[3];
    const float* a1s  = (const float*)d_in[4];
    const float* a1d  = (const float*)d_in[5];
    const float* b1   = (const float*)d_in[6];
    const float* W2   = (const float*)d_in[7];
    const float* a2s  = (const float*)d_in[8];
    const float* a2d  = (const float*)d_in[9];
    const float* b2   = (const float*)d_in[10];
    const float* fcW  = (const float*)d_in[11];
    const float* fcb  = (const float*)d_in[12];
    float* out = (float*)d_out;

    int* deg       = (int*)d_ws;                 // NN
    int* row_start = deg + NN;                   // NN
    int* csr_src   = row_start + NN;             // ET
    _Float16* x2h  = (_Float16*)(csr_src + ET);  // NN*32 halves (16B-aligned)
    float* Z       = (float*)(x2h + (size_t)NN * 32);  // NN*32 floats
    float* scoreS  = Z + (size_t)NN * 32;        // NN
    float* scoreD  = scoreS + NN;                // NN
    float* Y       = scoreD + NN;                // NN
    float2* c12    = (float2*)(Y + NN);          // 1 float2
    float* c2s     = (float*)(c12 + 1);          // 32
    float* c2d     = c2s + 32;                   // 32
    float* pooled  = c2d + 32;                   // NG*64
    float* cnts    = pooled + NG * 64;           // NG
    int*   bcnt    = (int*)(cnts + NG);          // NBUCK*NBLK
    int*   gcnt    = bcnt + NBUCK * NBLK;        // NBUCK
    int*   gbase   = gcnt + NBUCK;               // NBUCK
    int*   bedge   = (int*)Z;                    // alias: ET*4B = 6.8MB <= 12.8MB
                                                 // (dead before k_gat2 writes Z)

    const int B = 256;
    int gridW = (NN * 64 + B - 1) / B;           // wave-per-node kernels

    // ---- CSR build: two-level LDS counting sort, zero global atomics ----
    k_countA<<<NBLK, B, 0, stream>>>(dst, bcnt);
    k_scanrow<<<NBUCK, 64, 0, stream>>>(bcnt, gcnt);
    k_gscan<<<1, 1024, 0, stream>>>(gcnt, gbase);
    k_fillA<<<NBLK, B, 0, stream>>>(src, dst, bcnt, gbase, bedge);
    k_sortB<<<NBUCK, B, 0, stream>>>(gcnt, gbase, bedge, csr_src, deg, row_start);

    // ---- layer 1 (rank-1 scalar path) ----
    k_c1<<<1, 64, 0, stream>>>(W1, a1s, a1d, c12);
    k_gat1<<<gridW, B, 0, stream>>>(row_start, deg, csr_src, x, c12, Y);

    // ---- layer 2 pre (fp16 x2 + folded scores) ----
    k_c2<<<1, 64, 0, stream>>>(W2, a2s, a2d, c2s, c2d);
    k5_x2<<<(NN * 32 + B - 1) / B, B, 0, stream>>>(Y, W1, b1, c2s, c2d, x2h, scoreS, scoreD);

    // ---- layer 2 GAT (aggregate x2 -> Z) ----
    k_gat2<<<gridW, B, 0, stream>>>(row_start, deg, csr_src, scoreS, scoreD,
                                    (const half8*)x2h, Z);

    // ---- fused Z@W2 + relu + pool, then fc ----
    hipMemsetAsync(pooled, 0, (size_t)(NG * 64 + NG) * 4, stream);
    int gridP = ((NN + POOL_CHUNK - 1) / POOL_CHUNK * 64 + B - 1) / B;
    k_post_pool<<<gridP, B, 0, stream>>>(Z, W2, b2, batch, pooled, cnts);
    k7_fc<<<1, B, 0, stream>>>(pooled, cnts, fcW, fcb, out);
}

// Round 10
// 217.914 us; speedup vs baseline: 1.0585x; 1.0585x over previous
//
#include <hip/hip_runtime.h>

#define NN 100000
#define NE 1600000
#define ET (NE + NN)      // logical edges incl. self-loops
#define NG 256
#define NEG_SLOPE 0.2f
#define SM_EPS 1e-16f

// ---- two-level bucketed CSR build ----
#define BSHIFT 7                       // bucket = dst >> 7 (128 nodes/bucket)
#define NBUCK ((NN + 127) / 128)       // 782
#define EPB 8192                       // edges per block in count/fill passes
#define NBLK ((ET + EPB - 1) / EPB)    // 208
#define MAXB 5120                      // LDS staging cap (max bucket ~2400)

typedef _Float16 half8 __attribute__((ext_vector_type(8)));

__device__ __forceinline__ float lrelu(float x) { return x > 0.0f ? x : NEG_SLOPE * x; }

__device__ __forceinline__ void edge_sd(const int* __restrict__ src,
                                        const int* __restrict__ dst,
                                        int e, int& s, int& d) {
    if (e < NE) { s = src[e]; d = dst[e]; } else { s = e - NE; d = s; }
}

// ---- A1: per-block per-bucket counts (dst only) ----
__global__ void k_countA(const int* __restrict__ dst, int* __restrict__ bcnt) {
    __shared__ int cnt[NBUCK];
    int t = threadIdx.x, bid = blockIdx.x;
    for (int i = t; i < NBUCK; i += 256) cnt[i] = 0;
    __syncthreads();
    int e0 = bid * EPB;
    #pragma unroll
    for (int k = 0; k < EPB / 256; ++k) {
        int e = e0 + k * 256 + t;
        if (e < ET) {
            int d = (e < NE) ? dst[e] : (e - NE);
            atomicAdd(&cnt[d >> BSHIFT], 1);
        }
    }
    __syncthreads();
    for (int i = t; i < NBUCK; i += 256) bcnt[i * NBLK + bid] = cnt[i];
}

// ---- A2a: per-bucket exclusive prefix over blocks ----
__global__ void k_scanrow(int* __restrict__ bcnt, int* __restrict__ gcnt) {
    int row = blockIdx.x, lane = threadIdx.x;   // 64 threads
    int running = 0;
    const int chunks = (NBLK + 63) / 64;
    for (int c = 0; c < chunks; ++c) {
        int i = c * 64 + lane;
        int v = (i < NBLK) ? bcnt[row * NBLK + i] : 0;
        int incl = v;
        #pragma unroll
        for (int o = 1; o < 64; o <<= 1) {
            int u = __shfl_up(incl, o, 64);
            if (lane >= o) incl += u;
        }
        if (i < NBLK) bcnt[row * NBLK + i] = running + (incl - v);
        running += __shfl(incl, 63, 64);
    }
    if (lane == 0) gcnt[row] = running;
}

// ---- A2b: exclusive scan of bucket totals ----
__global__ void k_gscan(const int* __restrict__ gcnt, int* __restrict__ gbase) {
    __shared__ int sm[1024];
    int t = threadIdx.x;
    int v = (t < NBUCK) ? gcnt[t] : 0;
    sm[t] = v;
    __syncthreads();
    for (int off = 1; off < 1024; off <<= 1) {
        int u = (t >= off) ? sm[t - off] : 0;
        __syncthreads();
        sm[t] += u;
        __syncthreads();
    }
    if (t < NBUCK) gbase[t] = sm[t] - v;
}

// ---- A3: fill compact bucket-major packed edge array ((s<<7)|(d&127)) ----
__global__ void k_fillA(const int* __restrict__ src, const int* __restrict__ dst,
                        const int* __restrict__ bcnt, const int* __restrict__ gbase,
                        int* __restrict__ bedge) {
    __shared__ int base[NBUCK];
    __shared__ int lcnt[NBUCK];
    int t = threadIdx.x, bid = blockIdx.x;
    for (int i = t; i < NBUCK; i += 256) {
        base[i] = gbase[i] + bcnt[i * NBLK + bid];
        lcnt[i] = 0;
    }
    __syncthreads();
    int e0 = bid * EPB;
    #pragma unroll
    for (int k = 0; k < EPB / 256; ++k) {
        int e = e0 + k * 256 + t;
        if (e < ET) {
            int s, d; edge_sd(src, dst, e, s, d);
            int b = d >> BSHIFT;
            int rank = atomicAdd(&lcnt[b], 1);
            bedge[base[b] + rank] = (s << 7) | (d & 127);
        }
    }
}

// ---- B: per-bucket LDS counting sort -> coalesced CSR + deg + row_start ----
__global__ void k_sortB(const int* __restrict__ gcnt, const int* __restrict__ gbase,
                        const int* __restrict__ bedge,
                        int* __restrict__ csr_src, int* __restrict__ deg,
                        int* __restrict__ row_start) {
    __shared__ int lcnt[128], lstart[128], lcur[128];
    __shared__ int lout[MAXB];
    int b = blockIdx.x, t = threadIdx.x;        // 256 threads
    int cnt = gcnt[b];
    int base = gbase[b];
    const int* eb = bedge + base;
    if (t < 128) lcnt[t] = 0;
    __syncthreads();
    for (int i = t; i < cnt; i += 256)
        atomicAdd(&lcnt[eb[i] & 127], 1);
    __syncthreads();
    if (t < 128) lstart[t] = lcnt[t];
    __syncthreads();
    for (int off = 1; off < 128; off <<= 1) {
        int v = (t >= off && t < 128) ? lstart[t - off] : 0;
        __syncthreads();
        if (t < 128) lstart[t] += v;
        __syncthreads();
    }
    if (t < 128) {
        lstart[t] -= lcnt[t];          // exclusive
        lcur[t] = lstart[t];
    }
    __syncthreads();
    for (int i = t; i < cnt; i += 256) {
        int p = eb[i];
        int pos = atomicAdd(&lcur[p & 127], 1);
        lout[pos] = p >> 7;
    }
    __syncthreads();
    for (int i = t; i < cnt; i += 256)
        csr_src[base + i] = lout[i];
    int n = (b << BSHIFT) + t;
    if (t < 128 && n < NN) {
        deg[n] = lcnt[t];
        row_start[n] = base + lstart[t];
    }
}

// ---- layer-1 folded coefficients: c1s = W1·a1s, c1d = W1·a1d ----
__global__ void k_c1(const float* __restrict__ W1, const float* __restrict__ a1s,
                     const float* __restrict__ a1d, float2* __restrict__ c12) {
    int t = threadIdx.x;  // 64
    float w  = (t < 32) ? W1[t] : 0.0f;
    float vs = (t < 32) ? w * a1s[t] : 0.0f;
    float vd = (t < 32) ? w * a1d[t] : 0.0f;
    #pragma unroll
    for (int o = 32; o; o >>= 1) {
        vs += __shfl_xor(vs, o, 64);
        vd += __shfl_xor(vd, o, 64);
    }
    if (t == 0) *c12 = make_float2(vs, vd);
}

// ---- layer-2 folded score coefficients: c2s = W2@a2s, c2d = W2@a2d (32-vec) ----
__global__ void k_c2(const float* __restrict__ W2, const float* __restrict__ a2s,
                     const float* __restrict__ a2d,
                     float* __restrict__ c2s, float* __restrict__ c2d) {
    int k = threadIdx.x;   // 64 threads, first 32 active
    if (k >= 32) return;
    float vs = 0.0f, vd = 0.0f;
    for (int f = 0; f < 64; ++f) {
        float w = W2[k * 64 + f];
        vs += w * a2s[f];
        vd += w * a2d[f];
    }
    c2s[k] = vs; c2d[k] = vd;
}

// ---- layer 1: scalar GAT (rank-1 structure), one wave per node ----
__global__ void k_gat1(const int* __restrict__ row_start, const int* __restrict__ deg,
                       const int* __restrict__ csr_src, const float* __restrict__ x,
                       const float2* __restrict__ c12, float* __restrict__ Y) {
    int wid = (blockIdx.x * blockDim.x + threadIdx.x) >> 6;
    int lane = threadIdx.x & 63;
    if (wid >= NN) return;
    float2 c = *c12;                 // wave-uniform
    float xd = x[wid];
    int start = row_start[wid];
    int dg = deg[wid];

    float xs_reg = 0.0f, alpha_reg = -1e30f, m = -1e30f;
    if (lane < dg) {
        int s = csr_src[start + lane];
        xs_reg = x[s];
        alpha_reg = lrelu(c.x * xs_reg + c.y * xd);
        m = alpha_reg;
    }
    for (int i = lane + 64; i < dg; i += 64) {      // rare tail
        float xs = x[csr_src[start + i]];
        m = fmaxf(m, lrelu(c.x * xs + c.y * xd));
    }
    #pragma unroll
    for (int o = 32; o; o >>= 1) m = fmaxf(m, __shfl_xor(m, o, 64));

    float ev = (lane < dg) ? __expf(alpha_reg - m) : 0.0f;
    float sum = ev, wy = ev * xs_reg;
    for (int i = lane + 64; i < dg; i += 64) {      // rare tail
        float xs = x[csr_src[start + i]];
        float e2 = __expf(lrelu(c.x * xs + c.y * xd) - m);
        sum += e2; wy += e2 * xs;
    }
    #pragma unroll
    for (int o = 32; o; o >>= 1) {
        sum += __shfl_xor(sum, o, 64);
        wy  += __shfl_xor(wy, o, 64);
    }
    if (lane == 0) Y[wid] = wy / (sum + SM_EPS);
}

// ---- layer 2 pre: x2 = relu(Y*W1+b1) (fp16, NN x 32); ss/ds via folded c2 ----
__global__ void k5_x2(const float* __restrict__ Y,
                      const float* __restrict__ W1, const float* __restrict__ b1,
                      const float* __restrict__ c2s, const float* __restrict__ c2d,
                      _Float16* __restrict__ x2h,
                      float* __restrict__ ss, float* __restrict__ ds) {
    int tid = blockIdx.x * blockDim.x + threadIdx.x;
    if (tid >= NN * 32) return;
    int n = tid >> 5, k = tid & 31;
    float xv = Y[n] * W1[k] + b1[k];
    xv = xv > 0.0f ? xv : 0.0f;
    x2h[tid] = (_Float16)xv;
    float vs = xv * c2s[k];
    float vd = xv * c2d[k];
    #pragma unroll
    for (int m = 16; m; m >>= 1) {
        vs += __shfl_xor(vs, m, 32);
        vd += __shfl_xor(vd, m, 32);
    }
    if (k == 0) { ss[n] = vs; ds[n] = vd; }
}

// ---- layer 2 GAT: fp16 x2 gather (32-dim), 16 edges concurrent, Z = agg(x2) ----
__global__ void k_gat2(const int* __restrict__ row_start, const int* __restrict__ deg,
                       const int* __restrict__ csr_src,
                       const float* __restrict__ ss, const float* __restrict__ ds,
                       const half8* __restrict__ x2h, float* __restrict__ Z) {
    int wid = (blockIdx.x * blockDim.x + threadIdx.x) >> 6;
    int lane = threadIdx.x & 63;
    if (wid >= NN) return;
    int start = row_start[wid];
    int dg = deg[wid];
    float dsv = ds[wid];

    int   s_reg = 0;
    float alpha_reg = -1e30f, m = -1e30f;
    if (lane < dg) {
        s_reg = csr_src[start + lane];
        alpha_reg = lrelu(ss[s_reg] + dsv);
        m = alpha_reg;
    }
    for (int i = lane + 64; i < dg; i += 64) {
        int s = csr_src[start + i];
        m = fmaxf(m, lrelu(ss[s] + dsv));
    }
    #pragma unroll
    for (int o = 32; o; o >>= 1) m = fmaxf(m, __shfl_xor(m, o, 64));

    float sum = (lane < dg) ? __expf(alpha_reg - m) : 0.0f;
    for (int i = lane + 64; i < dg; i += 64) {
        int s = csr_src[start + i];
        sum += __expf(lrelu(ss[s] + dsv) - m);
    }
    #pragma unroll
    for (int o = 32; o; o >>= 1) sum += __shfl_xor(sum, o, 64);
    float inv = 1.0f / (sum + SM_EPS);

    // 16 edge-groups x half8 (8 features)/lane; uniform rounds for shfl safety
    int g  = lane >> 2;                 // edge group 0..15
    int f8 = lane & 3;                  // half8 index within 32 features
    float acc[8] = {0, 0, 0, 0, 0, 0, 0, 0};
    int nfull = dg < 64 ? dg : 64;
    int rounds = (nfull + 15) / 16;                 // wave-uniform
    for (int k = 0; k < rounds; ++k) {
        int t = g + k * 16;                         // <= 63 always
        int   s = __shfl(s_reg, t, 64);
        float a = __shfl(alpha_reg, t, 64);
        if (t < nfull) {
            float ev = __expf(a - m);
            half8 hv = x2h[(size_t)s * 4 + f8];
            #pragma unroll
            for (int j = 0; j < 8; ++j) acc[j] += ev * (float)hv[j];
        }
    }
    for (int t = 64 + g; t < dg; t += 16) {         // rare tail
        int s = csr_src[start + t];
        float ev = __expf(lrelu(ss[s] + dsv) - m);
        half8 hv = x2h[(size_t)s * 4 + f8];
        #pragma unroll
        for (int j = 0; j < 8; ++j) acc[j] += ev * (float)hv[j];
    }
    #pragma unroll
    for (int o = 4; o < 64; o <<= 1)
        #pragma unroll
        for (int j = 0; j < 8; ++j) acc[j] += __shfl_xor(acc[j], o, 64);
    if (lane < 4) {
        float4* dst = (float4*)&Z[(size_t)wid * 32 + lane * 8];
        dst[0] = make_float4(acc[0] * inv, acc[1] * inv, acc[2] * inv, acc[3] * inv);
        dst[1] = make_float4(acc[4] * inv, acc[5] * inv, acc[6] * inv, acc[7] * inv);
    }
}

// ---- post-projection: OUT = relu(Z @ W2 + b2), thread per (n,f) ----
__global__ void k_post(const float* __restrict__ Z, const float* __restrict__ W2,
                       const float* __restrict__ b2, float* __restrict__ OUT) {
    __shared__ float w2s[32 * 64];
    int t = threadIdx.x;
    for (int i = t; i < 32 * 64; i += 256) w2s[i] = W2[i];
    __syncthreads();
    int idx = blockIdx.x * 256 + t;
    if (idx >= NN * 64) return;
    int n = idx >> 6, f = idx & 63;
    const float4* zr = (const float4*)&Z[(size_t)n * 32];
    float acc = b2[f];
    #pragma unroll
    for (int k4 = 0; k4 < 8; ++k4) {
        float4 z = zr[k4];
        acc += z.x * w2s[(k4 * 4 + 0) * 64 + f] + z.y * w2s[(k4 * 4 + 1) * 64 + f]
             + z.z * w2s[(k4 * 4 + 2) * 64 + f] + z.w * w2s[(k4 * 4 + 3) * 64 + f];
    }
    OUT[idx] = acc > 0.0f ? acc : 0.0f;
}

// ---- pool (segmented, low-contention; input already relu'd+biased) + fc ----
#define POOL_CHUNK 64
__global__ void k6_pool(const float* __restrict__ OUT2,
                        const int* __restrict__ batch,
                        float* __restrict__ pooled, float* __restrict__ cnts) {
    int wid = (blockIdx.x * blockDim.x + threadIdx.x) >> 6;
    int lane = threadIdx.x & 63;
    int n0 = wid * POOL_CHUNK;
    if (n0 >= NN) return;
    int n1 = n0 + POOL_CHUNK; if (n1 > NN) n1 = NN;
    int curg = batch[n0];
    float acc = 0.0f;
    int cnt = 0;
    for (int n = n0; n < n1; ++n) {
        int g = batch[n];                       // wave-uniform
        if (g != curg) {
            atomicAdd(&pooled[curg * 64 + lane], acc);
            if (lane == 0) atomicAdd(&cnts[curg], (float)cnt);
            acc = 0.0f; cnt = 0; curg = g;
        }
        acc += OUT2[(size_t)n * 64 + lane];
        ++cnt;
    }
    atomicAdd(&pooled[curg * 64 + lane], acc);
    if (lane == 0) atomicAdd(&cnts[curg], (float)cnt);
}

__global__ void k7_fc(const float* __restrict__ pooled, const float* __restrict__ cnts,
                      const float* __restrict__ fcW, const float* __restrict__ fcb,
                      float* __restrict__ out) {
    int g = threadIdx.x;
    if (g >= NG) return;
    float c = fmaxf(cnts[g], 1.0f);
    float o0 = fcb[0], o1 = fcb[1];
    for (int f = 0; f < 64; ++f) {
        float p = pooled[g * 64 + f] / c;
        o0 += p * fcW[f * 2 + 0];
        o1 += p * fcW[f * 2 + 1];
    }
    out[g * 2 + 0] = o0;
    out[g * 2 + 1] = o1;
}

extern "C" void kernel_launch(void* const* d_in, const int* in_sizes, int n_in,
                              void* d_out, int out_size, void* d_ws, size_t ws_size,
                              hipStream_t stream) {
    const float* x    = (const float*)d_in[0];
    const int*   ei   = (const int*)d_in[1];
    const int*   src  = ei;
    const int*   dst  = ei + NE;
    const int*   batch= (const int*)d_in[2];
    const float* W1   = (const float*)d_in[3];
    const float* a1s  = (const float*)d_in[4];
    const float* a1d  = (const float*)d_in[5];
    const float* b1   = (const float*)d_in[6];
    const float* W2   = (const float*)d_in[7];
    const float* a2s  = (const float*)d_in[8];
    const float* a2d  = (const float*)d_in[9];
    const float* b2   = (const float*)d_in[10];
    const float* fcW  = (const float*)d_in[11];
    const float* fcb  = (const float*)d_in[12];
    float* out = (float*)d_out;

    int* deg       = (int*)d_ws;                 // NN
    int* row_start = deg + NN;                   // NN
    int* csr_src   = row_start + NN;             // ET
    _Float16* x2h  = (_Float16*)(csr_src + ET);  // NN*32 halves (16B-aligned)
    float* Z       = (float*)(x2h + (size_t)NN * 32);  // NN*32 floats
    float* OUT     = Z + (size_t)NN * 32;        // NN*64 floats
    float* scoreS  = OUT + (size_t)NN * 64;      // NN
    float* scoreD  = scoreS + NN;                // NN
    float* Y       = scoreD + NN;                // NN
    float2* c12    = (float2*)(Y + NN);          // 1 float2
    float* c2s     = (float*)(c12 + 1);          // 32
    float* c2d     = c2s + 32;                   // 32
    float* pooled  = c2d + 32;                   // NG*64
    float* cnts    = pooled + NG * 64;           // NG
    int*   bcnt    = (int*)(cnts + NG);          // NBUCK*NBLK
    int*   gcnt    = bcnt + NBUCK * NBLK;        // NBUCK
    int*   gbase   = gcnt + NBUCK;               // NBUCK
    int*   bedge   = (int*)Z;                    // alias: ET*4B = 6.8MB <= 12.8MB
                                                 // (dead before k_gat2 writes Z)

    const int B = 256;
    int gridW = (NN * 64 + B - 1) / B;           // wave-per-node kernels

    // ---- CSR build: two-level LDS counting sort, zero global atomics ----
    k_countA<<<NBLK, B, 0, stream>>>(dst, bcnt);
    k_scanrow<<<NBUCK, 64, 0, stream>>>(bcnt, gcnt);
    k_gscan<<<1, 1024, 0, stream>>>(gcnt, gbase);
    k_fillA<<<NBLK, B, 0, stream>>>(src, dst, bcnt, gbase, bedge);
    k_sortB<<<NBUCK, B, 0, stream>>>(gcnt, gbase, bedge, csr_src, deg, row_start);

    // ---- layer 1 (rank-1 scalar path) ----
    k_c1<<<1, 64, 0, stream>>>(W1, a1s, a1d, c12);
    k_gat1<<<gridW, B, 0, stream>>>(row_start, deg, csr_src, x, c12, Y);

    // ---- layer 2 pre (fp16 x2 + folded scores) ----
    k_c2<<<1, 64, 0, stream>>>(W2, a2s, a2d, c2s, c2d);
    k5_x2<<<(NN * 32 + B - 1) / B, B, 0, stream>>>(Y, W1, b1, c2s, c2d, x2h, scoreS, scoreD);

    // ---- layer 2 GAT (aggregate x2 -> Z) ----
    k_gat2<<<gridW, B, 0, stream>>>(row_start, deg, csr_src, scoreS, scoreD,
                                    (const half8*)x2h, Z);

    // ---- post-projection (parallel), pool, fc ----
    k_post<<<(NN * 64 + B - 1) / B, B, 0, stream>>>(Z, W2, b2, OUT);
    hipMemsetAsync(pooled, 0, (size_t)(NG * 64 + NG) * 4, stream);
    int gridP = ((NN + POOL_CHUNK - 1) / POOL_CHUNK * 64 + B - 1) / B;
    k6_pool<<<gridP, B, 0, stream>>>(OUT, batch, pooled, cnts);
    k7_fc<<<1, B, 0, stream>>>(pooled, cnts, fcW, fcb, out);
}